// Round 2
// baseline (1782.763 us; speedup 1.0000x reference)
//
#include <hip/hip_runtime.h>

#define MIN_NORM 1e-15f
#define RCPF(x)  __builtin_amdgcn_rcpf(x)
#define SQRTF(x) __builtin_amdgcn_sqrtf(x)

// butterfly sum within each 16-lane group (4 edges per wave)
__device__ __forceinline__ float rsum16(float v) {
    v += __shfl_xor(v, 1, 64);
    v += __shfl_xor(v, 2, 64);
    v += __shfl_xor(v, 4, 64);
    v += __shfl_xor(v, 8, 64);
    return v;
}

// tanh for x >= 0 via hardware exp; clamp keeps exp finite (real data x < ~2)
__device__ __forceinline__ float tanh_fast(float x) {
    float ex = __expf(fminf(2.f * x, 30.f));
    return (ex - 1.f) * RCPF(ex + 1.f);
}

// 4 edges per wave; lane = (sub=edge, g=dim-group), each lane owns dims [4g..4g+3]
__global__ __launch_bounds__(256) void rgat_edge_kernel(
    const float4* __restrict__ e,      // [N,16] float4 view
    const float4* __restrict__ rel,    // [32,16]
    const int*    __restrict__ head,
    const int*    __restrict__ tail,
    const int*    __restrict__ etype,  // 1-based
    float*        __restrict__ sums,   // [N,64] pre-zeroed
    int E)
{
    int tid   = blockIdx.x * 256 + (int)threadIdx.x;
    int waveG = tid >> 6;
    int lane  = (int)threadIdx.x & 63;
    int sub   = lane >> 4;
    int g     = lane & 15;
    int eid   = waveG * 4 + sub;
    bool active = eid < E;
    int ec = active ? eid : 0;

    int hi = head[ec];
    int ti = tail[ec];
    int ri = etype[ec] - 1;

    float4 h4 = e[(size_t)hi * 16 + g];
    float4 t4 = e[(size_t)ti * 16 + g];
    float4 r4 = rel[(size_t)ri * 16 + g];
    float h[4] = {h4.x, h4.y, h4.z, h4.w};
    float t[4] = {t4.x, t4.y, t4.z, t4.w};
    float r[4] = {r4.x, r4.y, r4.z, r4.w};
    float trl[4];

    float phh = 0.f, ptt = 0.f, prr = 0.f, pqq = 0.f, pht = 0.f, phr = 0.f;
#pragma unroll
    for (int k = 0; k < 4; ++k) {
        float q = t[k] + r[k];
        trl[k] = q;
        phh += h[k] * h[k];
        ptt += t[k] * t[k];
        prr += r[k] * r[k];
        pqq += q * q;
        pht += h[k] * t[k];
        phr += h[k] * r[k];
    }
    float hh   = rsum16(phh);
    float tt   = rsum16(ptt);
    float rr   = rsum16(prr);
    float ntr2 = rsum16(pqq);
    float ht   = rsum16(pht);
    float hr   = rsum16(phr);

    // p = expmap0(h)
    float nh  = fmaxf(SQRTF(hh), MIN_NORM);
    float th  = tanh_fast(nh);
    float scp = th * RCPF(nh);
    float p2  = th * th;
    float lam_inv = fmaxf(1.f - p2, MIN_NORM);   // = 2/lam
    float ilam    = RCPF(lam_inv);               // = lam/2

    // yt = tanh(0.5*lam*|t|) t/|t|
    float nt  = fmaxf(SQRTF(tt), MIN_NORM);
    float tht = tanh_fast(nt * ilam);
    float sct = tht * RCPF(nt);
    float y2t = tht * tht;
    float xyt = scp * sct * ht;

    // yr
    float nr   = fmaxf(SQRTF(rr), MIN_NORM);
    float thr_ = tanh_fast(nr * ilam);
    float scr  = thr_ * RCPF(nr);
    float y2r  = thr_ * thr_;
    float xyr  = scp * scr * hr;

    // a = mobius_add(p, yt)
    float alt  = 1.f + 2.f * xyt + y2t;
    float bet  = 1.f - p2;
    float dent = fmaxf(1.f + 2.f * xyt + p2 * y2t, MIN_NORM);
    float idt  = RCPF(dent);
    float a2 = (alt * alt * p2 + 2.f * alt * bet * xyt + bet * bet * y2t) * idt * idt;
    float pa = (alt * p2 + bet * xyt) * idt;

    // b = mobius_add(p, yr)
    float alr  = 1.f + 2.f * xyr + y2r;
    float denr = fmaxf(1.f + 2.f * xyr + p2 * y2r, MIN_NORM);
    float idr  = RCPF(denr);
    float b2 = (alr * alr * p2 + 2.f * alr * bet * xyr + bet * bet * y2r) * idr * idr;
    float pb = (alr * p2 + bet * xyr) * idr;

    // a.b (t.r via parallelogram)
    float trd  = 0.5f * (ntr2 - tt - rr);
    float ytyr = sct * scr * trd;
    float ab = (alt * alr * p2 + alt * bet * xyr + bet * alr * xyt + bet * bet * ytyr) * idt * idr;

    // m = mobius_add(a, b)
    float am   = 1.f + 2.f * ab + b2;
    float bm   = 1.f - a2;
    float denm = fmaxf(1.f + 2.f * ab + a2 * b2, MIN_NORM);
    float idm  = RCPF(denm);
    float m2  = (am * am * a2 + 2.f * am * bm * ab + bm * bm * b2) * idm * idm;
    float pmv = (am * pa + bm * pb) * idm;

    // project(m) — branchless
    float nm = fmaxf(SQRTF(m2), MIN_NORM);
    const float maxn = 1.f - 4e-3f;
    float sc = (nm > maxn) ? (maxn * RCPF(nm)) : 1.f;
    m2  *= sc * sc;
    pmv *= sc;

    // logmap(m, p) scalars
    float cs   = 1.f - 2.f * pmv + m2;
    float dsf  = 1.f - p2;
    float dens = fmaxf(1.f - 2.f * pmv + p2 * m2, MIN_NORM);
    float ids  = RCPF(dens);
    float s2 = (cs * cs * p2 - 2.f * cs * dsf * pmv + dsf * dsf * m2) * ids * ids;
    float ns  = fmaxf(SQRTF(s2), MIN_NORM);
    float xa  = fminf(ns, 1.f - 1e-7f);
    float ath = 0.5f * __logf((1.f + xa) * RCPF(1.f - xa));
    float lgs = lam_inv * ath * RCPF(ns);

    float iric = RCPF(fmaxf(SQRTF(ntr2), 1e-12f));

    // per-lane vectors + relu + atomic scatter
    float res[4];
#pragma unroll
    for (int k = 0; k < 4; ++k) {
        float p_l = scp * h[k];
        float a_l = (alt * p_l + bet * (sct * t[k])) * idt;
        float b_l = (alr * p_l + bet * (scr * r[k])) * idr;
        float m_l = (am * a_l + bm * b_l) * idm * sc;
        float s_l = (cs * (-p_l) + dsf * m_l) * ids;
        res[k] = fmaxf(lgs * s_l + 1e-7f * (trl[k] * iric), 0.f);
    }

    if (active) {
        float* dst = &sums[(size_t)hi * 64 + g * 4];
#pragma unroll
        for (int k = 0; k < 4; ++k) atomicAdd(dst + k, res[k]);
    }
}

// 4 entities per wave: l2-normalize(sums) (mean's count cancels), residual.
__global__ __launch_bounds__(256) void rgat_entity_kernel(
    const float4* __restrict__ sums,
    const float4* __restrict__ res_in,
    float4*       __restrict__ res_out,
    float4*       __restrict__ e_out,   // may be null
    int N)
{
    int tid   = blockIdx.x * 256 + (int)threadIdx.x;
    int waveG = tid >> 6;
    int lane  = (int)threadIdx.x & 63;
    int sub   = lane >> 4;
    int g     = lane & 15;
    int nid   = waveG * 4 + sub;
    bool active = nid < N;
    int nc = active ? nid : 0;
    size_t idx = (size_t)nc * 16 + g;

    float4 v = sums[idx];
    float n2 = rsum16(v.x * v.x + v.y * v.y + v.z * v.z + v.w * v.w);
    float inv = RCPF(fmaxf(SQRTF(n2), 1e-12f));
    v.x *= inv; v.y *= inv; v.z *= inv; v.w *= inv;

    float4 ri = res_in[idx];
    float4 o;
    o.x = 0.5f * ri.x + v.x;
    o.y = 0.5f * ri.y + v.y;
    o.z = 0.5f * ri.z + v.z;
    o.w = 0.5f * ri.w + v.w;

    if (active) {
        if (e_out) e_out[idx] = v;
        res_out[idx] = o;
    }
}

extern "C" void kernel_launch(void* const* d_in, const int* in_sizes, int n_in,
                              void* d_out, int out_size, void* d_ws, size_t ws_size,
                              hipStream_t stream)
{
    const float* ent   = (const float*)d_in[0];   // [N,64]
    const float* rel   = (const float*)d_in[1];   // [32,64]
    const int*   eidx  = (const int*)d_in[2];     // [2,E]
    const int*   etype = (const int*)d_in[3];     // [E]

    int E = in_sizes[3];
    int N = in_sizes[0] / 64;
    const int* head = eidx;
    const int* tail = eidx + E;

    float* A = (float*)d_ws;                  // hop-1 sums, then normalized e
    float* B = A + (size_t)N * 64;            // hop-2 sums
    size_t embBytes = (size_t)N * 64 * sizeof(float);

    hipMemsetAsync(d_ws, 0, 2 * embBytes, stream);

    dim3 blk(256);
    int edgeGrid = (E + 15) / 16;   // 4 waves/block × 4 edges/wave
    int entGrid  = (N + 15) / 16;

    float* out = (float*)d_out;

    // hop 1
    rgat_edge_kernel<<<edgeGrid, blk, 0, stream>>>(
        (const float4*)ent, (const float4*)rel, head, tail, etype, A, E);
    rgat_entity_kernel<<<entGrid, blk, 0, stream>>>(
        (const float4*)A, (const float4*)ent, (float4*)out, (float4*)A, N);
    // hop 2
    rgat_edge_kernel<<<edgeGrid, blk, 0, stream>>>(
        (const float4*)A, (const float4*)rel, head, tail, etype, B, E);
    rgat_entity_kernel<<<entGrid, blk, 0, stream>>>(
        (const float4*)B, (const float4*)out, (float4*)out, nullptr, N);
}

// Round 3
// 509.639 us; speedup vs baseline: 3.4981x; 3.4981x over previous
//
#include <hip/hip_runtime.h>

#define MIN_NORM 1e-15f
#define RCPF(x)  __builtin_amdgcn_rcpf(x)
#define SQRTF(x) __builtin_amdgcn_sqrtf(x)

// butterfly sum within each 16-lane group (4 edges per wave)
__device__ __forceinline__ float rsum16(float v) {
    v += __shfl_xor(v, 1, 64);
    v += __shfl_xor(v, 2, 64);
    v += __shfl_xor(v, 4, 64);
    v += __shfl_xor(v, 8, 64);
    return v;
}

// tanh for x >= 0 via hardware exp; clamp keeps exp finite (real data x < ~2)
__device__ __forceinline__ float tanh_fast(float x) {
    float ex = __expf(fminf(2.f * x, 30.f));
    return (ex - 1.f) * RCPF(ex + 1.f);
}

// 4 edges per wave; lane = (sub=edge, g); lane owns dims {g, g+16, g+32, g+48}
// => every load/atomic instruction: 16 consecutive dwords per sub-edge
//    (one full 64B cacheline), 4 sub-edges = 4 fully-covered lines/instr.
__global__ __launch_bounds__(256) void rgat_edge_kernel(
    const float* __restrict__ e,      // [N,64]
    const float* __restrict__ rel,    // [32,64]
    const int*   __restrict__ head,
    const int*   __restrict__ tail,
    const int*   __restrict__ etype,  // 1-based
    float*       __restrict__ sums,   // [N,64] pre-zeroed
    int E)
{
    int tid   = blockIdx.x * 256 + (int)threadIdx.x;
    int waveG = tid >> 6;
    int lane  = (int)threadIdx.x & 63;
    int sub   = lane >> 4;
    int g     = lane & 15;
    int eid   = waveG * 4 + sub;
    bool active = eid < E;
    int ec = active ? eid : 0;

    int hi = head[ec];
    int ti = tail[ec];
    int ri = etype[ec] - 1;

    const float* hrow = e   + (size_t)hi * 64 + g;
    const float* trow = e   + (size_t)ti * 64 + g;
    const float* rrow = rel + (size_t)ri * 64 + g;

    float h[4], t[4], r[4], trl[4];
#pragma unroll
    for (int k = 0; k < 4; ++k) {
        h[k] = hrow[k * 16];
        t[k] = trow[k * 16];
        r[k] = rrow[k * 16];
    }

    float phh = 0.f, ptt = 0.f, prr = 0.f, pqq = 0.f, pht = 0.f, phr = 0.f;
#pragma unroll
    for (int k = 0; k < 4; ++k) {
        float q = t[k] + r[k];
        trl[k] = q;
        phh += h[k] * h[k];
        ptt += t[k] * t[k];
        prr += r[k] * r[k];
        pqq += q * q;
        pht += h[k] * t[k];
        phr += h[k] * r[k];
    }
    float hh   = rsum16(phh);
    float tt   = rsum16(ptt);
    float rr   = rsum16(prr);
    float ntr2 = rsum16(pqq);
    float ht   = rsum16(pht);
    float hr   = rsum16(phr);

    // p = expmap0(h)
    float nh  = fmaxf(SQRTF(hh), MIN_NORM);
    float th  = tanh_fast(nh);
    float scp = th * RCPF(nh);
    float p2  = th * th;
    float lam_inv = fmaxf(1.f - p2, MIN_NORM);   // = 2/lam
    float ilam    = RCPF(lam_inv);               // = lam/2

    // yt = tanh(0.5*lam*|t|) t/|t|
    float nt  = fmaxf(SQRTF(tt), MIN_NORM);
    float tht = tanh_fast(nt * ilam);
    float sct = tht * RCPF(nt);
    float y2t = tht * tht;
    float xyt = scp * sct * ht;

    // yr
    float nr   = fmaxf(SQRTF(rr), MIN_NORM);
    float thr_ = tanh_fast(nr * ilam);
    float scr  = thr_ * RCPF(nr);
    float y2r  = thr_ * thr_;
    float xyr  = scp * scr * hr;

    // a = mobius_add(p, yt)
    float alt  = 1.f + 2.f * xyt + y2t;
    float bet  = 1.f - p2;
    float dent = fmaxf(1.f + 2.f * xyt + p2 * y2t, MIN_NORM);
    float idt  = RCPF(dent);
    float a2 = (alt * alt * p2 + 2.f * alt * bet * xyt + bet * bet * y2t) * idt * idt;
    float pa = (alt * p2 + bet * xyt) * idt;

    // b = mobius_add(p, yr)
    float alr  = 1.f + 2.f * xyr + y2r;
    float denr = fmaxf(1.f + 2.f * xyr + p2 * y2r, MIN_NORM);
    float idr  = RCPF(denr);
    float b2 = (alr * alr * p2 + 2.f * alr * bet * xyr + bet * bet * y2r) * idr * idr;
    float pb = (alr * p2 + bet * xyr) * idr;

    // a.b (t.r via parallelogram)
    float trd  = 0.5f * (ntr2 - tt - rr);
    float ytyr = sct * scr * trd;
    float ab = (alt * alr * p2 + alt * bet * xyr + bet * alr * xyt + bet * bet * ytyr) * idt * idr;

    // m = mobius_add(a, b)
    float am   = 1.f + 2.f * ab + b2;
    float bm   = 1.f - a2;
    float denm = fmaxf(1.f + 2.f * ab + a2 * b2, MIN_NORM);
    float idm  = RCPF(denm);
    float m2  = (am * am * a2 + 2.f * am * bm * ab + bm * bm * b2) * idm * idm;
    float pmv = (am * pa + bm * pb) * idm;

    // project(m) — branchless
    float nm = fmaxf(SQRTF(m2), MIN_NORM);
    const float maxn = 1.f - 4e-3f;
    float sc = (nm > maxn) ? (maxn * RCPF(nm)) : 1.f;
    m2  *= sc * sc;
    pmv *= sc;

    // logmap(m, p) scalars
    float cs   = 1.f - 2.f * pmv + m2;
    float dsf  = 1.f - p2;
    float dens = fmaxf(1.f - 2.f * pmv + p2 * m2, MIN_NORM);
    float ids  = RCPF(dens);
    float s2 = (cs * cs * p2 - 2.f * cs * dsf * pmv + dsf * dsf * m2) * ids * ids;
    float ns  = fmaxf(SQRTF(s2), MIN_NORM);
    float xa  = fminf(ns, 1.f - 1e-7f);
    float ath = 0.5f * __logf((1.f + xa) * RCPF(1.f - xa));
    float lgs = lam_inv * ath * RCPF(ns);

    float iric = RCPF(fmaxf(SQRTF(ntr2), 1e-12f));

    // per-lane vectors + relu
    float res[4];
#pragma unroll
    for (int k = 0; k < 4; ++k) {
        float p_l = scp * h[k];
        float a_l = (alt * p_l + bet * (sct * t[k])) * idt;
        float b_l = (alr * p_l + bet * (scr * r[k])) * idr;
        float m_l = (am * a_l + bm * b_l) * idm * sc;
        float s_l = (cs * (-p_l) + dsf * m_l) * ids;
        res[k] = fmaxf(lgs * s_l + 1e-7f * (trl[k] * iric), 0.f);
    }

    if (active) {
        float* dst = &sums[(size_t)hi * 64 + g];
#pragma unroll
        for (int k = 0; k < 4; ++k) atomicAdd(dst + k * 16, res[k]);
    }
}

// 4 entities per wave: l2-normalize(sums) (mean's count cancels), residual.
__global__ __launch_bounds__(256) void rgat_entity_kernel(
    const float4* __restrict__ sums,
    const float4* __restrict__ res_in,
    float4*       __restrict__ res_out,
    float4*       __restrict__ e_out,   // may be null
    int N)
{
    int tid   = blockIdx.x * 256 + (int)threadIdx.x;
    int waveG = tid >> 6;
    int lane  = (int)threadIdx.x & 63;
    int sub   = lane >> 4;
    int g     = lane & 15;
    int nid   = waveG * 4 + sub;
    bool active = nid < N;
    int nc = active ? nid : 0;
    size_t idx = (size_t)nc * 16 + g;

    float4 v = sums[idx];
    float n2 = rsum16(v.x * v.x + v.y * v.y + v.z * v.z + v.w * v.w);
    float inv = RCPF(fmaxf(SQRTF(n2), 1e-12f));
    v.x *= inv; v.y *= inv; v.z *= inv; v.w *= inv;

    float4 ri = res_in[idx];
    float4 o;
    o.x = 0.5f * ri.x + v.x;
    o.y = 0.5f * ri.y + v.y;
    o.z = 0.5f * ri.z + v.z;
    o.w = 0.5f * ri.w + v.w;

    if (active) {
        if (e_out) e_out[idx] = v;
        res_out[idx] = o;
    }
}

extern "C" void kernel_launch(void* const* d_in, const int* in_sizes, int n_in,
                              void* d_out, int out_size, void* d_ws, size_t ws_size,
                              hipStream_t stream)
{
    const float* ent   = (const float*)d_in[0];   // [N,64]
    const float* rel   = (const float*)d_in[1];   // [32,64]
    const int*   eidx  = (const int*)d_in[2];     // [2,E]
    const int*   etype = (const int*)d_in[3];     // [E]

    int E = in_sizes[3];
    int N = in_sizes[0] / 64;
    const int* head = eidx;
    const int* tail = eidx + E;

    float* A = (float*)d_ws;                  // hop-1 sums, then normalized e
    float* B = A + (size_t)N * 64;            // hop-2 sums
    size_t embBytes = (size_t)N * 64 * sizeof(float);

    hipMemsetAsync(d_ws, 0, 2 * embBytes, stream);

    dim3 blk(256);
    int edgeGrid = (E + 15) / 16;   // 4 waves/block × 4 edges/wave
    int entGrid  = (N + 15) / 16;

    float* out = (float*)d_out;

    // hop 1
    rgat_edge_kernel<<<edgeGrid, blk, 0, stream>>>(ent, rel, head, tail, etype, A, E);
    rgat_entity_kernel<<<entGrid, blk, 0, stream>>>(
        (const float4*)A, (const float4*)ent, (float4*)out, (float4*)A, N);
    // hop 2
    rgat_edge_kernel<<<edgeGrid, blk, 0, stream>>>(A, rel, head, tail, etype, B, E);
    rgat_entity_kernel<<<entGrid, blk, 0, stream>>>(
        (const float4*)B, (const float4*)out, (float4*)out, nullptr, N);
}